// Round 1
// baseline (344.533 us; speedup 1.0000x reference)
//
#include <hip/hip_runtime.h>
#include <cstdint>

#define DD 64
#define NROWS 2097152
#define NBLOCKS 2048
#define WAVES_TOTAL (NBLOCKS * 4)                 // 8192 waves
#define ROWS_PER_WAVE (NROWS / WAVES_TOTAL)       // 256 rows per wave
#define NQ (ROWS_PER_WAVE / 4)                    // 64 quad-row iterations
#define NSLOTS 3

typedef float float4v __attribute__((ext_vector_type(4)));

// ---------------- prep: K = P @ L @ U, loss = -sum(ulog) ----------------
__global__ void prep_kernel(const float* __restrict__ P,
                            const float* __restrict__ Lm,
                            const float* __restrict__ Um,
                            const float* __restrict__ usign,
                            const float* __restrict__ ulog,
                            float* __restrict__ K,
                            float* __restrict__ loss_out)
{
    __shared__ float Ls[DD][DD];
    __shared__ float Us[DD][DD];
    __shared__ int   pr[DD];
    const int t = threadIdx.x;

    for (int e = t; e < DD * DD; e += blockDim.x) {
        int i = e >> 6, j = e & 63;
        Ls[i][j] = (j < i) ? Lm[e] : (i == j ? 1.0f : 0.0f);
        Us[i][j] = (j > i) ? Um[e] : (i == j ? usign[i] * expf(ulog[i]) : 0.0f);
    }
    if (t < DD) {
        int c = 0;
        for (int j = 0; j < DD; ++j) if (P[t * DD + j] > 0.5f) c = j;
        pr[t] = c;
    }
    __syncthreads();

    for (int e = t; e < DD * DD; e += blockDim.x) {
        int i = e >> 6, j = e & 63;
        const float* lrow = Ls[pr[i]];
        float s = 0.0f;
        #pragma unroll
        for (int k = 0; k < DD; ++k) s = fmaf(lrow[k], Us[k][j], s);
        K[e] = s;
    }
    if (t == 0) {
        double s = 0.0;
        for (int i = 0; i < DD; ++i) s += (double)ulog[i];
        loss_out[0] = (float)(-s);
    }
}

// ---------------- main: out = x @ K ----------------
// One wave per 256 contiguous rows. Lane c holds K[:, c] in 64 VGPRs.
// x staged 4 rows (1 KB) per global_load_lds into a per-wave 3-slot LDS ring.
// Inner loop: uniform-address ds_read_b128 (HW broadcast) + 4 FMA chains.
__global__ __launch_bounds__(256, 5) void matmul_kernel(
    const float* __restrict__ x,
    const float* __restrict__ Kg,
    float* __restrict__ out)
{
    __shared__ __align__(16) float lds[4][NSLOTS][256];
    const int tid  = threadIdx.x;
    const int lane = tid & 63;
    const int wv   = tid >> 6;
    const int gwave = blockIdx.x * 4 + wv;
    const long long row0 = (long long)gwave * ROWS_PER_WAVE;

    // K column -> registers (L2-hot after the first waves)
    float Kr[DD];
    #pragma unroll
    for (int k = 0; k < DD; ++k) Kr[k] = Kg[k * DD + lane];
    __builtin_amdgcn_sched_barrier(0);
    asm volatile("s_waitcnt vmcnt(0)" ::: "memory");   // zero the vmcnt base
    __builtin_amdgcn_sched_barrier(0);

    const float* xbase = x + row0 * DD;
    float* obase = out + row0 * DD + lane;

    auto issue = [&](int q) {
        // stage rows 4q..4q+3 (1024 B) into slot q%3; lane i -> lds_base + 16*i
        const float* g = xbase + q * 256 + lane * 4;
        __builtin_amdgcn_global_load_lds(
            (__attribute__((address_space(1))) void*)g,
            (__attribute__((address_space(3))) void*)&lds[wv][q % NSLOTS][0],
            16, 0, 0);
    };

    issue(0); issue(1); issue(2);

    auto quad = [&](int q) {
        __builtin_amdgcn_sched_barrier(0);
        const float4v* s4 = (const float4v*)&lds[wv][q % NSLOTS][0];
        #pragma unroll
        for (int r = 0; r < 4; ++r) {
            float a0 = 0.f, a1 = 0.f, a2 = 0.f, a3 = 0.f;
            #pragma unroll
            for (int t16 = 0; t16 < 16; ++t16) {
                float4v xv = s4[r * 16 + t16];           // broadcast ds_read_b128
                a0 = fmaf(xv.x, Kr[4 * t16 + 0], a0);
                a1 = fmaf(xv.y, Kr[4 * t16 + 1], a1);
                a2 = fmaf(xv.z, Kr[4 * t16 + 2], a2);
                a3 = fmaf(xv.w, Kr[4 * t16 + 3], a3);
            }
            obase[(q * 4 + r) * DD] = (a0 + a1) + (a2 + a3);  // coalesced 256B store
        }
        __builtin_amdgcn_sched_barrier(0);
        if (q + 3 < NQ) issue(q + 3);     // refill the slot we just consumed
        __builtin_amdgcn_sched_barrier(0);
    };

    // Counted vmcnt: per steady iter the issue order is [4 stores, 1 load].
    // At top of iter q, #VMEM issued after L_q: q=0:2, q=1:6, 2..NQ-3:10.
    // Tail iters over-wait with vmcnt(0) (safe, negligible).
#define WAITV(W) do { asm volatile("s_waitcnt vmcnt(" #W ")" ::: "memory"); } while (0)
    WAITV(2);  quad(0);
    WAITV(6);  quad(1);
    for (int q = 2; q < NQ - 2; ++q) { WAITV(10); quad(q); }
    WAITV(0);  quad(NQ - 2);
    WAITV(0);  quad(NQ - 1);
#undef WAITV
}

extern "C" void kernel_launch(void* const* d_in, const int* in_sizes, int n_in,
                              void* d_out, int out_size, void* d_ws, size_t ws_size,
                              hipStream_t stream)
{
    const float* x  = (const float*)d_in[0];
    const float* P  = (const float*)d_in[1];
    const float* Lm = (const float*)d_in[2];
    const float* Um = (const float*)d_in[3];
    const float* sg = (const float*)d_in[4];
    const float* lg = (const float*)d_in[5];
    float* out = (float*)d_out;
    float* K   = (float*)d_ws;   // 64*64*4 = 16 KB scratch

    prep_kernel<<<1, 256, 0, stream>>>(P, Lm, Um, sg, lg, K, out + (size_t)NROWS * DD);
    matmul_kernel<<<NBLOCKS, 256, 0, stream>>>(x, K, out);
}

// Round 2
// 289.693 us; speedup vs baseline: 1.1893x; 1.1893x over previous
//
#include <hip/hip_runtime.h>
#include <hip/hip_bf16.h>
#include <cstdint>

#define DD 64
#define NROWS 2097152
#define NBLOCKS 2048
#define TILES_PER_WAVE 16   // 8192 waves * 16 tiles * 16 rows = 2M rows

typedef float f32x4 __attribute__((ext_vector_type(4)));
typedef short bf16x8 __attribute__((ext_vector_type(8)));

static __device__ __forceinline__ short f2bf(float f) {
    union { __hip_bfloat16 b; unsigned short u; } cv;
    cv.b = __float2bfloat16(f);
    return (short)cv.u;
}

// ---------------- prep: K = P @ L @ U, loss = -sum(ulog) ----------------
__global__ void prep_kernel(const float* __restrict__ P,
                            const float* __restrict__ Lm,
                            const float* __restrict__ Um,
                            const float* __restrict__ usign,
                            const float* __restrict__ ulog,
                            float* __restrict__ K,
                            float* __restrict__ loss_out)
{
    __shared__ float Ls[DD][DD];
    __shared__ float Us[DD][DD];
    __shared__ int   pr[DD];
    const int t = threadIdx.x;

    for (int e = t; e < DD * DD; e += blockDim.x) {
        int i = e >> 6, j = e & 63;
        Ls[i][j] = (j < i) ? Lm[e] : (i == j ? 1.0f : 0.0f);
        Us[i][j] = (j > i) ? Um[e] : (i == j ? usign[i] * expf(ulog[i]) : 0.0f);
    }
    if (t < DD) {
        int c = 0;
        for (int j = 0; j < DD; ++j) if (P[t * DD + j] > 0.5f) c = j;
        pr[t] = c;
    }
    __syncthreads();

    for (int e = t; e < DD * DD; e += blockDim.x) {
        int i = e >> 6, j = e & 63;
        const float* lrow = Ls[pr[i]];
        float s = 0.0f;
        #pragma unroll
        for (int k = 0; k < DD; ++k) s = fmaf(lrow[k], Us[k][j], s);
        K[e] = s;
    }
    if (t == 0) {
        double s = 0.0;
        for (int i = 0; i < DD; ++i) s += (double)ulog[i];
        loss_out[0] = (float)(-s);
    }
}

// ---------------- main: out = x @ K via bf16 MFMA ----------------
// 16x16x32 bf16 MFMA. A-frag: lane holds A[lane&15][(lane>>4)*8 + j], j=0..7.
// B-frag: lane holds B[(lane>>4)*8 + j][lane&15].  C/D: col=lane&15,
// row=(lane>>4)*4+reg  [verified m89/m91].  K resident as 8 B-frags in VGPRs.
// No LDS, no barriers; 1-deep ping-pong prefetch with counted vmcnt.
__global__ __launch_bounds__(256, 4) void matmul_kernel(
    const float* __restrict__ x,
    const float* __restrict__ Kg,
    float* __restrict__ out)
{
    const int tid  = threadIdx.x;
    const int lane = tid & 63;
    const int wv   = tid >> 6;
    const long long gwave = (long long)blockIdx.x * 4 + wv;
    const long long tile0 = gwave * TILES_PER_WAVE;

    const int lrow = lane & 15;   // m (A) / n (B,C) index
    const int kgrp = lane >> 4;   // 0..3 k-group

    // ---- K -> B fragments (once; K is 16 KB, L2-hot) ----
    bf16x8 bfr[2][4];
    #pragma unroll
    for (int kt = 0; kt < 2; ++kt)
        #pragma unroll
        for (int nt = 0; nt < 4; ++nt)
            #pragma unroll
            for (int j = 0; j < 8; ++j)
                bfr[kt][nt][j] = f2bf(Kg[(kt * 32 + kgrp * 8 + j) * DD + nt * 16 + lrow]);

    f32x4 bufA[4], bufB[4];

    auto load_tile = [&](long long t, f32x4 (&buf)[4]) {
        const long long m0 = t * 16;
        const f32x4* p = (const f32x4*)(x + (m0 + lrow) * DD + kgrp * 8);
        buf[0] = p[0];   // kt=0, j=0..3
        buf[1] = p[1];   // kt=0, j=4..7
        buf[2] = p[8];   // kt=1, j=0..3
        buf[3] = p[9];   // kt=1, j=4..7
    };

    auto compute_store = [&](long long t, f32x4 (&buf)[4]) {
        bf16x8 afr[2];
        #pragma unroll
        for (int kt = 0; kt < 2; ++kt)
            #pragma unroll
            for (int j = 0; j < 8; ++j)
                afr[kt][j] = f2bf(j < 4 ? buf[kt * 2][j] : buf[kt * 2 + 1][j - 4]);

        f32x4 acc[4];
        #pragma unroll
        for (int nt = 0; nt < 4; ++nt) acc[nt] = (f32x4){0.f, 0.f, 0.f, 0.f};
        #pragma unroll
        for (int kt = 0; kt < 2; ++kt)
            #pragma unroll
            for (int nt = 0; nt < 4; ++nt)
                acc[nt] = __builtin_amdgcn_mfma_f32_16x16x32_bf16(
                    afr[kt], bfr[kt][nt], acc[nt], 0, 0, 0);

        const long long m0 = t * 16;
        float* ob = out + (m0 + kgrp * 4) * DD + lrow;
        #pragma unroll
        for (int nt = 0; nt < 4; ++nt)
            #pragma unroll
            for (int r = 0; r < 4; ++r)
                ob[(long long)r * DD + nt * 16] = acc[nt][r];
    };

#define WAITV(W) do { asm volatile("s_waitcnt vmcnt(" #W ")" ::: "memory"); } while (0)
    // VMEM order per step t: [4 loads(t+1)] ... [16 stores(t)].  In-order vmcnt:
    // cur(t) is guaranteed done when outstanding <= (#issued after cur).
    auto step = [&](int t, f32x4 (&cur)[4], f32x4 (&nxt)[4]) {
        if (t + 1 < TILES_PER_WAVE) load_tile(tile0 + t + 1, nxt);
        if (t == 0)                        WAITV(4);   // after cur: loads(t+1)=4
        else if (t == TILES_PER_WAVE - 1)  WAITV(16);  // after cur: stores(t-1)=16
        else                               WAITV(20);  // stores(t-1)=16 + loads(t+1)=4
        compute_store(tile0 + t, cur);
    };
#undef WAITV

    load_tile(tile0, bufA);
    for (int t = 0; t < TILES_PER_WAVE; t += 2) {
        step(t,     bufA, bufB);
        step(t + 1, bufB, bufA);
    }
}

extern "C" void kernel_launch(void* const* d_in, const int* in_sizes, int n_in,
                              void* d_out, int out_size, void* d_ws, size_t ws_size,
                              hipStream_t stream)
{
    const float* x  = (const float*)d_in[0];
    const float* P  = (const float*)d_in[1];
    const float* Lm = (const float*)d_in[2];
    const float* Um = (const float*)d_in[3];
    const float* sg = (const float*)d_in[4];
    const float* lg = (const float*)d_in[5];
    float* out = (float*)d_out;
    float* K   = (float*)d_ws;   // 64*64*4 = 16 KB scratch

    prep_kernel<<<1, 256, 0, stream>>>(P, Lm, Um, sg, lg, K, out + (size_t)NROWS * DD);
    matmul_kernel<<<NBLOCKS, 256, 0, stream>>>(x, K, out);
}

// Round 3
// 257.149 us; speedup vs baseline: 1.3398x; 1.1266x over previous
//
#include <hip/hip_runtime.h>
#include <hip/hip_bf16.h>
#include <cstdint>

#define DD 64
#define NROWS 2097152
#define NBLOCKS 2048
#define TILES_PER_WAVE 16   // 8192 waves * 16 tiles * 16 rows = 2M rows

typedef float f32x4 __attribute__((ext_vector_type(4)));
typedef short bf16x8 __attribute__((ext_vector_type(8)));

static __device__ __forceinline__ short f2bf(float f) {
    union { __hip_bfloat16 b; unsigned short u; } cv;
    cv.b = __float2bfloat16(f);
    return (short)cv.u;
}

// ---------------- prep: K = P @ L @ U, loss = -sum(ulog) ----------------
__global__ void prep_kernel(const float* __restrict__ P,
                            const float* __restrict__ Lm,
                            const float* __restrict__ Um,
                            const float* __restrict__ usign,
                            const float* __restrict__ ulog,
                            float* __restrict__ K,
                            float* __restrict__ loss_out)
{
    __shared__ float Ls[DD][DD];
    __shared__ float Us[DD][DD];
    __shared__ int   pr[DD];
    const int t = threadIdx.x;

    for (int e = t; e < DD * DD; e += blockDim.x) {
        int i = e >> 6, j = e & 63;
        Ls[i][j] = (j < i) ? Lm[e] : (i == j ? 1.0f : 0.0f);
        Us[i][j] = (j > i) ? Um[e] : (i == j ? usign[i] * expf(ulog[i]) : 0.0f);
    }
    if (t < DD) {
        int c = 0;
        for (int j = 0; j < DD; ++j) if (P[t * DD + j] > 0.5f) c = j;
        pr[t] = c;
    }
    __syncthreads();

    for (int e = t; e < DD * DD; e += blockDim.x) {
        int i = e >> 6, j = e & 63;
        const float* lrow = Ls[pr[i]];
        float s = 0.0f;
        #pragma unroll
        for (int k = 0; k < DD; ++k) s = fmaf(lrow[k], Us[k][j], s);
        K[e] = s;
    }
    if (t == 0) {
        double s = 0.0;
        for (int i = 0; i < DD; ++i) s += (double)ulog[i];
        loss_out[0] = (float)(-s);
    }
}

// ---------------- main: out = x @ K via bf16 MFMA ----------------
// 16x16x32 bf16 MFMA, K resident as B-frags in VGPRs, no LDS/barriers.
// 3-deep register prefetch with exact in-order counted vmcnt.
// Stores are NON-TEMPORAL: out is write-once, keep it out of L2/L3 so the
// x read stream retains Infinity-Cache residency.
__global__ __launch_bounds__(256, 4) void matmul_kernel(
    const float* __restrict__ x,
    const float* __restrict__ Kg,
    float* __restrict__ out)
{
    const int tid  = threadIdx.x;
    const int lane = tid & 63;
    const int wv   = tid >> 6;
    const long long gwave = (long long)blockIdx.x * 4 + wv;
    const long long tile0 = gwave * TILES_PER_WAVE;

    const int lrow = lane & 15;   // m (A) / n (B,C) index
    const int kgrp = lane >> 4;   // 0..3 k-group

    // ---- K -> B fragments (once; K is 16 KB, L2-hot) ----
    bf16x8 bfr[2][4];
    #pragma unroll
    for (int kt = 0; kt < 2; ++kt)
        #pragma unroll
        for (int nt = 0; nt < 4; ++nt)
            #pragma unroll
            for (int j = 0; j < 8; ++j)
                bfr[kt][nt][j] = f2bf(Kg[(kt * 32 + kgrp * 8 + j) * DD + nt * 16 + lrow]);
    __builtin_amdgcn_sched_barrier(0);
    asm volatile("s_waitcnt vmcnt(0)" ::: "memory");   // zero the vmcnt base
    __builtin_amdgcn_sched_barrier(0);

    f32x4 b0[4], b1[4], b2[4];

    auto LT = [&](long long t, f32x4 (&buf)[4]) {
        const long long m0 = t * 16;
        const f32x4* p = (const f32x4*)(x + (m0 + lrow) * DD + kgrp * 8);
        buf[0] = p[0];   // kt=0, j=0..3
        buf[1] = p[1];   // kt=0, j=4..7
        buf[2] = p[8];   // kt=1, j=0..3
        buf[3] = p[9];   // kt=1, j=4..7
    };

    auto CS = [&](long long t, f32x4 (&buf)[4]) {
        bf16x8 afr[2];
        #pragma unroll
        for (int kt = 0; kt < 2; ++kt)
            #pragma unroll
            for (int j = 0; j < 8; ++j)
                afr[kt][j] = f2bf(j < 4 ? buf[kt * 2][j] : buf[kt * 2 + 1][j - 4]);

        f32x4 acc[4];
        #pragma unroll
        for (int nt = 0; nt < 4; ++nt) acc[nt] = (f32x4){0.f, 0.f, 0.f, 0.f};
        #pragma unroll
        for (int kt = 0; kt < 2; ++kt)
            #pragma unroll
            for (int nt = 0; nt < 4; ++nt)
                acc[nt] = __builtin_amdgcn_mfma_f32_16x16x32_bf16(
                    afr[kt], bfr[kt][nt], acc[nt], 0, 0, 0);

        const long long m0 = t * 16;
        float* ob = out + (m0 + kgrp * 4) * DD + lrow;
        #pragma unroll
        for (int nt = 0; nt < 4; ++nt)
            #pragma unroll
            for (int r = 0; r < 4; ++r)
                __builtin_nontemporal_store(acc[nt][r], &ob[(long long)r * DD + nt * 16]);
    };

#define WAITV(W) do { asm volatile("s_waitcnt vmcnt(" #W ")" ::: "memory"); } while (0)
    // Issue order: L0 L1 L2 | W C0 L3 | W C1 L4 | ... | W C(t) L(t+3) | ...
    // In-order vmcnt at W(t): ops younger than L(t):
    //   t=0: L1,L2 = 8.  t=1: L2,S0,L3 = 24.  t=2..13: S(t-2),L(t+1),S(t-1),L(t+2) = 40.
    //   t=14: S12,L15,S13 = 36.  t=15: S13,S14 = 32.
    LT(tile0 + 0, b0);
    LT(tile0 + 1, b1);
    LT(tile0 + 2, b2);

    WAITV(8);  CS(tile0 + 0, b0); LT(tile0 + 3, b0);
    WAITV(24); CS(tile0 + 1, b1); LT(tile0 + 4, b1);
    for (int t = 2; t + 2 <= TILES_PER_WAVE - 3; t += 3) {   // t = 2,5,8,11
        WAITV(40); CS(tile0 + t,     b2);                        LT(tile0 + t + 3, b2);
        WAITV(40); CS(tile0 + t + 1, b0);                        LT(tile0 + t + 4, b0);
        WAITV(40); CS(tile0 + t + 2, b1); if (t + 5 < TILES_PER_WAVE) LT(tile0 + t + 5, b1);
    }
    WAITV(36); CS(tile0 + 14, b2);
    WAITV(32); CS(tile0 + 15, b0);
#undef WAITV
}

extern "C" void kernel_launch(void* const* d_in, const int* in_sizes, int n_in,
                              void* d_out, int out_size, void* d_ws, size_t ws_size,
                              hipStream_t stream)
{
    const float* x  = (const float*)d_in[0];
    const float* P  = (const float*)d_in[1];
    const float* Lm = (const float*)d_in[2];
    const float* Um = (const float*)d_in[3];
    const float* sg = (const float*)d_in[4];
    const float* lg = (const float*)d_in[5];
    float* out = (float*)d_out;
    float* K   = (float*)d_ws;   // 64*64*4 = 16 KB scratch

    prep_kernel<<<1, 256, 0, stream>>>(P, Lm, Um, sg, lg, K, out + (size_t)NROWS * DD);
    matmul_kernel<<<NBLOCKS, 256, 0, stream>>>(x, K, out);
}